// Round 12
// baseline (1244.843 us; speedup 1.0000x reference)
//
#include <hip/hip_runtime.h>
#include <cstdint>
#include <cstddef>

namespace {

constexpr int B = 16, S = 768, BS = B * S, D = 512, FF = 2048, L = 6;
constexpr float EPS = 1e-5f;

typedef float f32x4 __attribute__((ext_vector_type(4)));
typedef _Float16 f16x8 __attribute__((ext_vector_type(8)));

__device__ __forceinline__ float wave_sum(float v) {
#pragma unroll
  for (int o = 32; o > 0; o >>= 1) v += __shfl_xor(v, o, 64);
  return v;
}

__device__ __forceinline__ short f16b(float x) {
  const _Float16 h = (_Float16)x;
  return __builtin_bit_cast(short, h);
}
__device__ __forceinline__ float h2f(short s) {
  return (float)__builtin_bit_cast(_Float16, s);
}

// ---- async global->LDS, 16B per lane ------------------------------------
__device__ __forceinline__ void gload16(const void* g, void* l) {
  __builtin_amdgcn_global_load_lds(
      (const __attribute__((address_space(1))) void*)g,
      (__attribute__((address_space(3))) void*)l, 16, 0, 0);
}

// LDS tile [rows][BK/8 slots of 16B]. Bank fix: global slot gsl = sl0 ^
// (row & (SLOTS-1)); LDS linear (rule #21). 2-way residual = free (m136).

// =========================================================================
// fp16 GEMM 128x128, BK=64 (FF1, N=2048: grid 1536, balanced).
// =========================================================================
template <bool RELU, bool PACK>
__global__ __launch_bounds__(256, 3) void gemm_h(
    const short* __restrict__ A, int lda, const short* __restrict__ Wt,
    int ldw, int Klen, const float* __restrict__ bias,
    short* __restrict__ ph, int ldp) {
  __shared__ alignas(16) short sAh[8192], sBh[8192];
  const int tid = threadIdx.x;
  const unsigned Nt = gridDim.x;
  const unsigned lin = blockIdx.y * Nt + blockIdx.x;
  const unsigned cpx = (Nt * gridDim.y) >> 3;
  const unsigned swz = (lin & 7) * cpx + (lin >> 3);
  const int bn = (int)(swz % Nt) * 128, bm = (int)(swz / Nt) * 128;
  const int wave = tid >> 6, lane = tid & 63;
  const int wr = (wave >> 1) * 64, wc = (wave & 1) * 64;
  const int lr = lane & 15, sl = lane >> 4;
  const short* Ab = A + (size_t)bm * lda;
  const short* Wb = Wt + (size_t)bn * ldw;
  f32x4 acc[4][4] = {};
  for (int kk = 0; kk < Klen; kk += 64) {
#pragma unroll
    for (int jj = 0; jj < 4; ++jj) {
      const int G = jj * 256 + tid;
      const int srow = G >> 3, sl0 = G & 7;
      const int gsl = sl0 ^ (srow & 7);
      const int dst = G * 8;
      gload16(Ab + (size_t)srow * lda + kk + gsl * 8, &sAh[dst]);
      gload16(Wb + (size_t)srow * ldw + kk + gsl * 8, &sBh[dst]);
    }
    __syncthreads();
#pragma unroll
    for (int ks = 0; ks < 2; ++ks) {
      f16x8 aH[4], bH[4];
#pragma unroll
      for (int m = 0; m < 4; ++m) {
        const int r = wr + m * 16 + lr;
        aH[m] = *(const f16x8*)&sAh[r * 64 + (((ks * 4 + sl) ^ (r & 7)) * 8)];
      }
#pragma unroll
      for (int n = 0; n < 4; ++n) {
        const int r = wc + n * 16 + lr;
        bH[n] = *(const f16x8*)&sBh[r * 64 + (((ks * 4 + sl) ^ (r & 7)) * 8)];
      }
#pragma unroll
      for (int m = 0; m < 4; ++m)
#pragma unroll
        for (int n = 0; n < 4; ++n)
          acc[m][n] = __builtin_amdgcn_mfma_f32_16x16x32_f16(aH[m], bH[n],
                                                             acc[m][n], 0, 0, 0);
    }
    __syncthreads();
  }
  const int r4 = sl * 4;
#pragma unroll
  for (int m = 0; m < 4; ++m) {
#pragma unroll
    for (int r = 0; r < 4; ++r) {
      const int mm = bm + wr + m * 16 + r4 + r;
#pragma unroll
      for (int n = 0; n < 4; ++n) {
        const int col = bn + wc + n * 16 + lr;
        float v = acc[m][n][r] + bias[col];
        if (RELU) v = fmaxf(v, 0.f);
        if (PACK) ph[(size_t)mm * ldp + col] = f16b(v);
      }
    }
  }
}

// =========================================================================
// fp16 GEMM 128x64, templated BK (64 or 128). grid 768 = 3/CU balanced.
// BK=128: 32 MFMA/barrier-pair, LDS 48KB (occupancy 3 holds).
// RESM: 0 none, 1 f32 resid (rmod), 2 f16 resid. CSUM: column partials.
// =========================================================================
template <bool RELU, int RESM, bool PACK, bool CSUM, int BK>
__global__ __launch_bounds__(256, 3) void gemm_h64(
    const short* __restrict__ A, int lda, const short* __restrict__ Wt,
    int ldw, int Klen, const float* __restrict__ bias,
    const float* __restrict__ resid, const short* __restrict__ residS,
    int ldr, int rmod, short* __restrict__ ph, int ldp,
    float* __restrict__ part) {
  constexpr int GPR = BK / 8;             // 16B granules per row
  constexpr int AR = 128 * GPR / 256;     // A staging rounds
  constexpr int BR = 64 * GPR / 256;      // B staging rounds
  constexpr int KS = BK / 32;             // MFMA k-subchunks
  __shared__ alignas(16) short sAh[128 * BK], sBh[64 * BK];
  __shared__ float csLds[2][64];
  const int tid = threadIdx.x;
  const unsigned Nt = gridDim.x;  // 8
  const unsigned lin = blockIdx.y * Nt + blockIdx.x;
  const unsigned cpx = (Nt * gridDim.y) >> 3;
  const unsigned swz = (lin & 7) * cpx + (lin >> 3);
  const int bn = (int)(swz % Nt) * 64, bmt = (int)(swz / Nt);
  const int bm = bmt * 128;
  const int wave = tid >> 6, lane = tid & 63;
  const int wr = (wave >> 1) * 64, wc = (wave & 1) * 32;
  const int lr = lane & 15, sl = lane >> 4;
  const short* Ab = A + (size_t)bm * lda;
  const short* Wb = Wt + (size_t)bn * ldw;
  f32x4 acc[4][2] = {};
  for (int kk = 0; kk < Klen; kk += BK) {
#pragma unroll
    for (int jj = 0; jj < AR; ++jj) {
      const int G = jj * 256 + tid;
      const int srow = G / GPR, sl0 = G % GPR;
      const int gsl = sl0 ^ (srow & (GPR - 1));
      gload16(Ab + (size_t)srow * lda + kk + gsl * 8, &sAh[G * 8]);
    }
#pragma unroll
    for (int jj = 0; jj < BR; ++jj) {
      const int G = jj * 256 + tid;
      const int srow = G / GPR, sl0 = G % GPR;
      const int gsl = sl0 ^ (srow & (GPR - 1));
      gload16(Wb + (size_t)srow * ldw + kk + gsl * 8, &sBh[G * 8]);
    }
    __syncthreads();
#pragma unroll
    for (int ks = 0; ks < KS; ++ks) {
      f16x8 aH[4], bH[2];
#pragma unroll
      for (int m = 0; m < 4; ++m) {
        const int r = wr + m * 16 + lr;
        aH[m] = *(const f16x8*)
            &sAh[r * BK + (((ks * 4 + sl) ^ (r & (GPR - 1))) * 8)];
      }
#pragma unroll
      for (int n = 0; n < 2; ++n) {
        const int r = wc + n * 16 + lr;
        bH[n] = *(const f16x8*)
            &sBh[r * BK + (((ks * 4 + sl) ^ (r & (GPR - 1))) * 8)];
      }
#pragma unroll
      for (int m = 0; m < 4; ++m)
#pragma unroll
        for (int n = 0; n < 2; ++n)
          acc[m][n] = __builtin_amdgcn_mfma_f32_16x16x32_f16(aH[m], bH[n],
                                                             acc[m][n], 0, 0, 0);
    }
    __syncthreads();
  }
  const int r4 = sl * 4;
  float cs[2] = {0.f, 0.f};
#pragma unroll
  for (int m = 0; m < 4; ++m) {
#pragma unroll
    for (int r = 0; r < 4; ++r) {
      const int mm = bm + wr + m * 16 + r4 + r;
#pragma unroll
      for (int n = 0; n < 2; ++n) {
        const int col = bn + wc + n * 16 + lr;
        float v = acc[m][n][r] + bias[col];
        if (RELU) v = fmaxf(v, 0.f);
        if (RESM == 1) {
          const int rr = rmod ? (mm % rmod) : mm;
          v += resid[(size_t)rr * ldr + col];
        }
        if (RESM == 2) v += h2f(residS[(size_t)mm * ldr + col]);
        if (PACK) ph[(size_t)mm * ldp + col] = f16b(v);
        if (CSUM) cs[n] += v;
      }
    }
  }
  if constexpr (CSUM) {
#pragma unroll
    for (int n = 0; n < 2; ++n) {
      cs[n] += __shfl_xor(cs[n], 16, 64);
      cs[n] += __shfl_xor(cs[n], 32, 64);
    }
    if (sl == 0) {
      csLds[wave >> 1][wc + lr] = cs[0];
      csLds[wave >> 1][wc + 16 + lr] = cs[1];
    }
    __syncthreads();
    if (tid < 64)
      part[(size_t)bmt * 512 + bn + tid] = csLds[0][tid] + csLds[1][tid];
  }
}

// =========================================================================
// Conv, BN=64/BK=128, all 4 z per block, single f16 partial out.
// Per block: 4z x {2 side taps, K=512} (alpha-scaled) + merged-center K=512
// (alpha baked in W_mix). 36 barrier-pairs x 32 MFMA. grid 768 = 3/CU.
// =========================================================================
__global__ __launch_bounds__(256, 3) void conv_zp_k(
    const short* __restrict__ hp, const short* __restrict__ wt8,
    const short* __restrict__ wmix, const float* __restrict__ alpha,
    const short* __restrict__ zpadS, short* __restrict__ P) {
  __shared__ alignas(16) short sAh[16384], sBh[8192];
  const int tid = threadIdx.x;
  const unsigned lin = blockIdx.x;
  const unsigned swz = (lin & 7) * 96 + (lin >> 3);
  const int bn = (int)(swz & 7) * 64;
  const int bmt = (int)(swz >> 3);  // 0..95
  const int b = bmt / 6, s0 = (bmt % 6) * 128, gm0 = bmt * 128;
  const int wave = tid >> 6, lane = tid & 63;
  const int wr = (wave >> 1) * 64, wc = (wave & 1) * 32;
  const int lr = lane & 15, sl = lane >> 4;
  const short* hb = hp + (size_t)b * S * 512;
  f32x4 accF[4][2] = {};
#pragma unroll
  for (int z = 0; z < 4; ++z) {
    const int dd = 1 << z;
    f32x4 acc[4][2] = {};
    for (int kk = 0; kk < 1024; kk += 128) {
      const int tap = kk >> 9;  // 0: -d, 1: +d
      const int koff = kk & 511;
      const int off = tap ? dd : -dd;
#pragma unroll
      for (int jj = 0; jj < 8; ++jj) {
        const int G = jj * 256 + tid;
        const int srow = G >> 4, sl0 = G & 15;
        const int gsl = sl0 ^ (srow & 15);
        const int gs = s0 + srow + off;
        const bool inb = ((unsigned)gs < (unsigned)S);
        const short* aBase = hb + (size_t)gs * 512 + koff + gsl * 8;
        gload16(inb ? aBase : zpadS, &sAh[G * 8]);
      }
#pragma unroll
      for (int jj = 0; jj < 4; ++jj) {
        const int G = jj * 256 + tid;
        const int srow = G >> 4, sl0 = G & 15;
        const int gsl = sl0 ^ (srow & 15);
        gload16(wt8 + ((size_t)((z * 2 + tap) * 512 + bn + srow)) * 512 +
                    koff + gsl * 8,
                &sBh[G * 8]);
      }
      __syncthreads();
#pragma unroll
      for (int ks = 0; ks < 4; ++ks) {
        f16x8 aH[4], bH[2];
#pragma unroll
        for (int m = 0; m < 4; ++m) {
          const int r = wr + m * 16 + lr;
          aH[m] = *(const f16x8*)
              &sAh[r * 128 + (((ks * 4 + sl) ^ (r & 15)) * 8)];
        }
#pragma unroll
        for (int n = 0; n < 2; ++n) {
          const int r = wc + n * 16 + lr;
          bH[n] = *(const f16x8*)
              &sBh[r * 128 + (((ks * 4 + sl) ^ (r & 15)) * 8)];
        }
#pragma unroll
        for (int m = 0; m < 4; ++m)
#pragma unroll
          for (int n = 0; n < 2; ++n)
            acc[m][n] = __builtin_amdgcn_mfma_f32_16x16x32_f16(
                aH[m], bH[n], acc[m][n], 0, 0, 0);
      }
      __syncthreads();
    }
    const float al = alpha[b * 4 + z];
#pragma unroll
    for (int m = 0; m < 4; ++m)
#pragma unroll
      for (int n = 0; n < 2; ++n)
#pragma unroll
        for (int r = 0; r < 4; ++r) accF[m][n][r] += al * acc[m][n][r];
  }
  // ---- merged-center K=512 (alpha baked into W_mix) ----
  const short* Wm = wmix + (size_t)b * 512 * 512;
  for (int kc = 0; kc < 512; kc += 128) {
#pragma unroll
    for (int jj = 0; jj < 8; ++jj) {
      const int G = jj * 256 + tid;
      const int srow = G >> 4, sl0 = G & 15;
      const int gsl = sl0 ^ (srow & 15);
      gload16(hb + (size_t)(s0 + srow) * 512 + kc + gsl * 8, &sAh[G * 8]);
    }
#pragma unroll
    for (int jj = 0; jj < 4; ++jj) {
      const int G = jj * 256 + tid;
      const int srow = G >> 4, sl0 = G & 15;
      const int gsl = sl0 ^ (srow & 15);
      gload16(Wm + (size_t)(bn + srow) * 512 + kc + gsl * 8, &sBh[G * 8]);
    }
    __syncthreads();
#pragma unroll
    for (int ks = 0; ks < 4; ++ks) {
      f16x8 aH[4], bH[2];
#pragma unroll
      for (int m = 0; m < 4; ++m) {
        const int r = wr + m * 16 + lr;
        aH[m] =
            *(const f16x8*)&sAh[r * 128 + (((ks * 4 + sl) ^ (r & 15)) * 8)];
      }
#pragma unroll
      for (int n = 0; n < 2; ++n) {
        const int r = wc + n * 16 + lr;
        bH[n] =
            *(const f16x8*)&sBh[r * 128 + (((ks * 4 + sl) ^ (r & 15)) * 8)];
      }
#pragma unroll
      for (int m = 0; m < 4; ++m)
#pragma unroll
        for (int n = 0; n < 2; ++n)
          accF[m][n] = __builtin_amdgcn_mfma_f32_16x16x32_f16(
              aH[m], bH[n], accF[m][n], 0, 0, 0);
    }
    __syncthreads();
  }
  const int r4 = sl * 4;
#pragma unroll
  for (int m = 0; m < 4; ++m)
#pragma unroll
    for (int r = 0; r < 4; ++r) {
      const int mm = gm0 + wr + m * 16 + r4 + r;
#pragma unroll
      for (int n = 0; n < 2; ++n)
        P[(size_t)mm * D + bn + wc + n * 16 + lr] = f16b(accF[m][n][r]);
    }
}

// ---- fused conv-combine + LN1 -> LN2, all-f16 state (single partial) -----
__global__ __launch_bounds__(256) void ln3_k(
    const short* __restrict__ P0, const short* __restrict__ hpk,
    const float* __restrict__ cbmix, const float* __restrict__ g1,
    const float* __restrict__ b1, const float* __restrict__ g2,
    const float* __restrict__ b2, short* __restrict__ pout) {
  const int row = blockIdx.x * 4 + (threadIdx.x >> 6);
  const int lane = threadIdx.x & 63;
  const int bb = row / S;
  const size_t base = (size_t)row * D;
  float v[8];
  float s = 0.f;
#pragma unroll
  for (int j = 0; j < 8; ++j) {
    const int c = lane + 64 * j;
    v[j] = h2f(P0[base + c]) + h2f(hpk[base + c]) + cbmix[(size_t)bb * D + c];
    s += v[j];
  }
  s = wave_sum(s);
  const float m1 = s * (1.f / D);
  float q = 0.f;
#pragma unroll
  for (int j = 0; j < 8; ++j) { const float d = v[j] - m1; q += d * d; }
  q = wave_sum(q);
  const float r1 = rsqrtf(q * (1.f / D) + EPS);
  float y[8];
  float s2 = 0.f;
#pragma unroll
  for (int j = 0; j < 8; ++j) {
    const int c = lane + 64 * j;
    y[j] = (v[j] - m1) * r1 * g1[c] + b1[c];
    s2 += y[j];
  }
  s2 = wave_sum(s2);
  const float m2 = s2 * (1.f / D);
  float q2 = 0.f;
#pragma unroll
  for (int j = 0; j < 8; ++j) { const float d = y[j] - m2; q2 += d * d; }
  q2 = wave_sum(q2);
  const float r2 = rsqrtf(q2 * (1.f / D) + EPS);
  short* prow = pout + base;
#pragma unroll
  for (int j = 0; j < 8; ++j) {
    const int c = lane + 64 * j;
    prow[c] = f16b((y[j] - m2) * r2 * g2[c] + b2[c]);
  }
}

// ---- 64x64 transpose-pack tile body --------------------------------------
__device__ __forceinline__ void pack_tile(const float* __restrict__ W,
                                          short* __restrict__ out, int K,
                                          int N, int n0, int k0) {
  __shared__ short t[64][68];
  const int ln = threadIdx.x & 63, w4 = threadIdx.x >> 6;
#pragma unroll
  for (int it = 0; it < 16; ++it) {
    const int kr = it * 4 + w4;
    t[kr][ln] = f16b(W[(size_t)(k0 + kr) * N + n0 + ln]);
  }
  __syncthreads();
#pragma unroll
  for (int it = 0; it < 16; ++it) {
    const int nr = it * 4 + w4;
    out[(size_t)(n0 + nr) * K + k0 + ln] = t[ln][nr];
  }
}

// ---- W transpose-pack: (K,N) f32 -> (N,K) fp16 ---------------------------
__global__ __launch_bounds__(256) void pack_wt_k(const float* __restrict__ W,
                                                 short* __restrict__ out,
                                                 int K, int N) {
  pack_tile(W, out, K, N, blockIdx.x * 64, blockIdx.y * 64);
}

// ---- all-FF pack: 12 weights (6 x {ffw1, ffw2}), 3072 blocks -------------
__global__ __launch_bounds__(256) void pack_ff_all_k(
    const float* __restrict__ ffw1, const float* __restrict__ ffw2,
    short* __restrict__ outAll) {
  const int bid = blockIdx.x;
  const int l = bid >> 9;
  const int r = bid & 511;
  if (r < 256) {
    pack_tile(ffw1 + (size_t)l * D * FF, outAll + (size_t)l * 2097152, 512,
              2048, (r & 31) * 64, (r >> 5) * 64);
  } else {
    const int r2 = r - 256;
    pack_tile(ffw2 + (size_t)l * FF * D,
              outAll + (size_t)l * 2097152 + 1048576, 2048, 512,
              (r2 & 7) * 64, (r2 >> 3) * 64);
  }
}

// ---- all conv side-tap pack: (L,4,O,I,3) taps {0,2} -> (L,8,O,I) ---------
__global__ __launch_bounds__(256) void pack_conv8_all_k(
    const float* __restrict__ cw, short* __restrict__ out) {
  const size_t idx = (size_t)blockIdx.x * 256 + threadIdx.x;  // 6*8*512*512
  const int c = (int)(idx & 511);
  const int o = (int)((idx >> 9) & 511);
  const int seg = (int)((idx >> 18) & 7);
  const int l = (int)(idx >> 21);
  const int z = seg >> 1, t = (seg & 1) * 2;
  out[idx] = f16b(cw[((size_t)l * 4 * D * D + ((size_t)z * D + o) * D + c) * 3 + t]);
}

// ---- W_mix[b] = sum_z alpha[b,z] * W[z,center]  (f32 mix -> fp16) --------
__global__ __launch_bounds__(256) void wmix_k(const float* __restrict__ cw,
                                              const float* __restrict__ alpha,
                                              short* __restrict__ wm) {
  __shared__ float sal[64];
  if (threadIdx.x < 64) sal[threadIdx.x] = alpha[threadIdx.x];
  __syncthreads();
  const int idx = blockIdx.x * 256 + threadIdx.x;  // 262144 (o,c)
  const int c = idx & 511, o = idx >> 9;
  float w[4];
#pragma unroll
  for (int z = 0; z < 4; ++z)
    w[z] = cw[(((size_t)z * D + o) * D + c) * 3 + 1];
#pragma unroll
  for (int b = 0; b < 16; ++b) {
    const float v = sal[b * 4 + 0] * w[0] + sal[b * 4 + 1] * w[1] +
                    sal[b * 4 + 2] * w[2] + sal[b * 4 + 3] * w[3];
    wm[((size_t)b * D + o) * D + c] = f16b(v);
  }
}

__global__ __launch_bounds__(256) void zero_k(float* __restrict__ p) {
  p[threadIdx.x] = 0.f;
  p[threadIdx.x + 256] = 0.f;
}

// ---- alpha from GEMM column partials; cb_mix[b] = sum a_z cb_z -----------
__global__ __launch_bounds__(64) void alpha_k(const float* __restrict__ part,
                                              const float* __restrict__ wmw,
                                              const float* __restrict__ wmb,
                                              const float* __restrict__ cb,
                                              float* __restrict__ alpha,
                                              float* __restrict__ cbmix) {
  const int b = blockIdx.x, t = threadIdx.x;
  float p0 = 0, p1 = 0, p2 = 0, p3 = 0;
  for (int d = t; d < D; d += 64) {
    float xm = 0;
#pragma unroll
    for (int c = 0; c < 6; ++c) xm += part[((size_t)(b * 6 + c)) * D + d];
    xm *= (1.f / S);
    p0 += xm * wmw[d * 4 + 0];
    p1 += xm * wmw[d * 4 + 1];
    p2 += xm * wmw[d * 4 + 2];
    p3 += xm * wmw[d * 4 + 3];
  }
  p0 = wave_sum(p0); p1 = wave_sum(p1);
  p2 = wave_sum(p2); p3 = wave_sum(p3);
  const float l0 = p0 + wmb[0], l1 = p1 + wmb[1];
  const float l2 = p2 + wmb[2], l3 = p3 + wmb[3];
  const float mx = fmaxf(fmaxf(l0, l1), fmaxf(l2, l3));
  const float e0 = expf(l0 - mx), e1 = expf(l1 - mx);
  const float e2 = expf(l2 - mx), e3 = expf(l3 - mx);
  const float inv = 1.f / (e0 + e1 + e2 + e3);
  const float a0 = e0 * inv, a1 = e1 * inv, a2 = e2 * inv, a3 = e3 * inv;
  if (t == 0) {
    alpha[b * 4 + 0] = a0;
    alpha[b * 4 + 1] = a1;
    alpha[b * 4 + 2] = a2;
    alpha[b * 4 + 3] = a3;
  }
  for (int c = t; c < D; c += 64)
    cbmix[(size_t)b * D + c] =
        a0 * cb[c] + a1 * cb[D + c] + a2 * cb[2 * D + c] + a3 * cb[3 * D + c];
}

// ---- embedding gather-mean, hi-pack out ----------------------------------
__global__ __launch_bounds__(256) void embed_k(const int* __restrict__ xe,
                                               const float* __restrict__ emb,
                                               short* __restrict__ out) {
  const int r = blockIdx.x;
  int idx[8];
#pragma unroll
  for (int j = 0; j < 8; ++j) idx[j] = xe[r * 8 + j];
  short* o = out + (size_t)r * 512;
  for (int d = threadIdx.x; d < D; d += 256) {
    float s = 0.f;
#pragma unroll
    for (int j = 0; j < 8; ++j) s += emb[(size_t)idx[j] * D + d];
    o[d] = f16b(s * 0.125f);
  }
}

// ---- L2-normalize rows of (BS,64), hi-pack out ---------------------------
__global__ __launch_bounds__(256) void norml2_k(const float* __restrict__ x,
                                                short* __restrict__ out) {
  const int r = blockIdx.x * 4 + (threadIdx.x >> 6);
  const int lane = threadIdx.x & 63;
  const float v = x[(size_t)r * 64 + lane];
  const float s = wave_sum(v * v);
  const float nrm = fmaxf(sqrtf(s), 1e-12f);
  out[(size_t)r * 64 + lane] = f16b(v / nrm);
}

// ---- classifier head (reads GEMM column partials) ------------------------
__global__ __launch_bounds__(256) void head_k(
    const float* __restrict__ part, const float* __restrict__ pw1,
    const float* __restrict__ pb1, const float* __restrict__ pw2,
    const float* __restrict__ pb2, float* __restrict__ out) {
  __shared__ float hg[D];
  __shared__ float red[256];
  const int b = blockIdx.x, t = threadIdx.x;
  for (int d = t; d < D; d += 256) {
    float s = 0.f;
#pragma unroll
    for (int c = 0; c < 6; ++c) s += part[((size_t)(b * 6 + c)) * D + d];
    hg[d] = s * (1.f / S);
  }
  __syncthreads();
  float s = pb1[t];
  for (int d = 0; d < D; ++d) s = fmaf(hg[d], pw1[(size_t)d * 256 + t], s);
  s = fmaxf(s, 0.f);
  red[t] = s * pw2[t];
  __syncthreads();
  for (int o = 128; o > 0; o >>= 1) {
    if (t < o) red[t] += red[t + o];
    __syncthreads();
  }
  if (t == 0) out[b] = red[0] + pb2[0];
}

}  // namespace

extern "C" void kernel_launch(void* const* d_in, const int* in_sizes, int n_in,
                              void* d_out, int out_size, void* d_ws,
                              size_t ws_size, hipStream_t stream) {
  const float* x_cog = (const float*)d_in[0];
  const float* cw1 = (const float*)d_in[1];
  const float* cb1 = (const float*)d_in[2];
  const float* cw2 = (const float*)d_in[3];
  const float* cb2 = (const float*)d_in[4];
  const float* env_emb = (const float*)d_in[5];
  const float* ew1 = (const float*)d_in[6];
  const float* eb1 = (const float*)d_in[7];
  const float* ew2 = (const float*)d_in[8];
  const float* eb2 = (const float*)d_in[9];
  const float* fw1 = (const float*)d_in[10];
  const float* fb1 = (const float*)d_in[11];
  const float* fw2 = (const float*)d_in[12];
  const float* fb2 = (const float*)d_in[13];
  const float* pos_enc = (const float*)d_in[14];
  const float* conv_w = (const float*)d_in[15];
  const float* conv_b = (const float*)d_in[16];
  const float* wm_w = (const float*)d_in[17];
  const float* wm_b = (const float*)d_in[18];
  // d_in[19..21] = ssm_w/ssm_b/A_log: no-ops (y scalar-per-row cancels in LN2)
  const float* ffw1 = (const float*)d_in[22];
  const float* ffb1 = (const float*)d_in[23];
  const float* ffw2 = (const float*)d_in[24];
  const float* ffb2 = (const float*)d_in[25];
  const float* g1 = (const float*)d_in[26];
  const float* be1 = (const float*)d_in[27];
  const float* g2 = (const float*)d_in[28];
  const float* be2 = (const float*)d_in[29];
  const float* pw1 = (const float*)d_in[30];
  const float* pb1 = (const float*)d_in[31];
  const float* pw2 = (const float*)d_in[32];
  const float* pb2 = (const float*)d_in[33];
  const int* x_env = (const int*)d_in[34];
  float* out = (float*)d_out;

  // ---- arena (~163 MB, no aliasing except liveness-clean CONC=APFF) ------
  float* ws = (float*)d_ws;
  float* PART2 = ws;                       // 96x512 f32
  float* ALPHAB = PART2 + 65536;           // 64
  float* ZPADF = ALPHAB + 64;              // 512 zero page
  float* CBMIX = ZPADF + 512;              // 16x512 f32
  short* R = (short*)(CBMIX + 8192);
  short* WFFALL = R;                       // 6x2x1,048,576 [0, 12,582,912)
  short* WC8ALL = R + 12582912;            // 6x8x512x512   [12,582,912, 25,165,824)
  short* WMIX = R + 25165824;              // 16x512x512    [25,165,824, 29,360,128)
  short* convPh = R + 29360128;            // 12288x512     [29,360,128, 35,651,584)
  short* HPACK = R + 35651584;             // 12288x512     [35,651,584, 41,943,040)
  short* APFF = R + 41943040;              // 12288x2048    [41,943,040, 67,108,864)
  short* CONC = APFF;                      // frontend alias (CONC dead before
                                           // APFF first written in layer 0)
  short* PK1 = R + 67108864;               // 12288x512
  short* PK2 = R + 73400320;               // 12288x512
  short* WPBF = R + 79691776;              // frontend W pack (<=524,288)

  const dim3 blk(256);
  const dim3 gS(8, 96, 1);    // N=512, BN=64 -> 768 blocks (3/CU)
  const dim3 gF(16, 96, 1);   // N=2048, BN=128 -> 1536 blocks

  zero_k<<<1, blk, 0, stream>>>(ZPADF);
  pack_ff_all_k<<<3072, blk, 0, stream>>>(ffw1, ffw2, WFFALL);
  pack_conv8_all_k<<<49152, blk, 0, stream>>>(conv_w, WC8ALL);

  // ---- frontend -----------------------------------------------------------
  norml2_k<<<BS / 4, blk, 0, stream>>>(x_cog, PK1);
  pack_wt_k<<<dim3(8, 1), blk, 0, stream>>>(cw1, WPBF, 64, 512);
  gemm_h64<true, 0, true, false, 64><<<gS, blk, 0, stream>>>(
      PK1, 64, WPBF, 64, 64, cb1, nullptr, nullptr, 0, 0, PK2, 512, nullptr);
  pack_wt_k<<<dim3(8, 8), blk, 0, stream>>>(cw2, WPBF, 512, 512);
  gemm_h64<false, 0, true, false, 128><<<gS, blk, 0, stream>>>(
      PK2, 512, WPBF, 512, 512, cb2, nullptr, nullptr, 0, 0, CONC, 2048,
      nullptr);
  embed_k<<<BS, blk, 0, stream>>>(x_env, env_emb, PK1);
  pack_wt_k<<<dim3(8, 8), blk, 0, stream>>>(ew1, WPBF, 512, 512);
  gemm_h64<true, 0, true, false, 128><<<gS, blk, 0, stream>>>(
      PK1, 512, WPBF, 512, 512, eb1, nullptr, nullptr, 0, 0, PK2, 512,
      nullptr);
  pack_wt_k<<<dim3(8, 8), blk, 0, stream>>>(ew2, WPBF, 512, 512);
  gemm_h64<false, 0, true, false, 128><<<gS, blk, 0, stream>>>(
      PK2, 512, WPBF, 512, 512, eb2, nullptr, nullptr, 0, 0, CONC + 512, 2048,
      nullptr);
  pack_wt_k<<<dim3(8, 16), blk, 0, stream>>>(fw1, WPBF, 1024, 512);
  gemm_h64<true, 0, true, false, 128><<<gS, blk, 0, stream>>>(
      CONC, 2048, WPBF, 1024, 1024, fb1, nullptr, nullptr, 0, 0, PK1, 512,
      nullptr);
  pack_wt_k<<<dim3(8, 8), blk, 0, stream>>>(fw2, WPBF, 512, 512);
  // h = (PK1@fw2 + fb2) + pos_enc -> HPACK hi + PART2 colsums
  gemm_h64<false, 1, true, true, 128><<<gS, blk, 0, stream>>>(
      PK1, 512, WPBF, 512, 512, fb2, pos_enc, nullptr, 512, S, HPACK, 512,
      PART2);

  // ---- layers (all-f16 state, 6 dispatches each) -------------------------
  for (int l = 0; l < L; ++l) {
    const float* cwl = conv_w + (size_t)l * 4 * D * D * 3;
    alpha_k<<<B, dim3(64), 0, stream>>>(PART2, wm_w + (size_t)l * D * 4,
                                        wm_b + l * 4,
                                        conv_b + (size_t)l * 4 * D, ALPHAB,
                                        CBMIX);
    wmix_k<<<1024, blk, 0, stream>>>(cwl, ALPHAB, WMIX);
    conv_zp_k<<<768, blk, 0, stream>>>(HPACK, WC8ALL + (size_t)l * 2097152,
                                       WMIX, ALPHAB, (const short*)ZPADF,
                                       convPh);
    // h2 = LN2(LN1(P+h+cb_mix)) -> HPACK (in-place h -> h2)
    ln3_k<<<BS / 4, blk, 0, stream>>>(convPh, HPACK, CBMIX, g1 + l * D,
                                      be1 + l * D, g2 + l * D, be2 + l * D,
                                      HPACK);
    gemm_h<true, true><<<gF, blk, 0, stream>>>(
        HPACK, 512, WFFALL + (size_t)l * 2097152, 512, 512,
        ffb1 + (size_t)l * FF, APFF, 2048);
    // new h = APFF@ffw2 + ffb2 + h2(f16) -> HPACK (in-place) + PART2 colsums
    gemm_h64<false, 2, true, true, 128><<<gS, blk, 0, stream>>>(
        APFF, 2048, WFFALL + (size_t)l * 2097152 + 1048576, 2048, 2048,
        ffb2 + (size_t)l * D, nullptr, HPACK, 512, 0, HPACK, 512, PART2);
  }

  // ---- head ---------------------------------------------------------------
  head_k<<<B, blk, 0, stream>>>(PART2, pw1, pb1, pw2, pb2, out);
}

// Round 13
// 1142.966 us; speedup vs baseline: 1.0891x; 1.0891x over previous
//
#include <hip/hip_runtime.h>
#include <cstdint>
#include <cstddef>

namespace {

constexpr int B = 16, S = 768, BS = B * S, D = 512, FF = 2048, L = 6;
constexpr float EPS = 1e-5f;

typedef float f32x4 __attribute__((ext_vector_type(4)));
typedef _Float16 f16x8 __attribute__((ext_vector_type(8)));

__device__ __forceinline__ float wave_sum(float v) {
#pragma unroll
  for (int o = 32; o > 0; o >>= 1) v += __shfl_xor(v, o, 64);
  return v;
}

__device__ __forceinline__ short f16b(float x) {
  const _Float16 h = (_Float16)x;
  return __builtin_bit_cast(short, h);
}
__device__ __forceinline__ float h2f(short s) {
  return (float)__builtin_bit_cast(_Float16, s);
}

// ---- async global->LDS, 16B per lane ------------------------------------
__device__ __forceinline__ void gload16(const void* g, void* l) {
  __builtin_amdgcn_global_load_lds(
      (const __attribute__((address_space(1))) void*)g,
      (__attribute__((address_space(3))) void*)l, 16, 0, 0);
}

// LDS tile [rows][BK/8 slots of 16B]. Bank fix: global slot gsl = sl0 ^
// (row & (SLOTS-1)); LDS linear (rule #21). 2-way residual = free (m136).

// =========================================================================
// fp16 GEMM 128x128, BK=64 (FF1, N=2048: grid 1536, balanced).
// =========================================================================
template <bool RELU, bool PACK>
__global__ __launch_bounds__(256, 3) void gemm_h(
    const short* __restrict__ A, int lda, const short* __restrict__ Wt,
    int ldw, int Klen, const float* __restrict__ bias,
    short* __restrict__ ph, int ldp) {
  __shared__ alignas(16) short sAh[8192], sBh[8192];
  const int tid = threadIdx.x;
  const unsigned Nt = gridDim.x;
  const unsigned lin = blockIdx.y * Nt + blockIdx.x;
  const unsigned cpx = (Nt * gridDim.y) >> 3;
  const unsigned swz = (lin & 7) * cpx + (lin >> 3);
  const int bn = (int)(swz % Nt) * 128, bm = (int)(swz / Nt) * 128;
  const int wave = tid >> 6, lane = tid & 63;
  const int wr = (wave >> 1) * 64, wc = (wave & 1) * 64;
  const int lr = lane & 15, sl = lane >> 4;
  const short* Ab = A + (size_t)bm * lda;
  const short* Wb = Wt + (size_t)bn * ldw;
  f32x4 acc[4][4] = {};
  for (int kk = 0; kk < Klen; kk += 64) {
#pragma unroll
    for (int jj = 0; jj < 4; ++jj) {
      const int G = jj * 256 + tid;
      const int srow = G >> 3, sl0 = G & 7;
      const int gsl = sl0 ^ (srow & 7);
      const int dst = G * 8;
      gload16(Ab + (size_t)srow * lda + kk + gsl * 8, &sAh[dst]);
      gload16(Wb + (size_t)srow * ldw + kk + gsl * 8, &sBh[dst]);
    }
    __syncthreads();
#pragma unroll
    for (int ks = 0; ks < 2; ++ks) {
      f16x8 aH[4], bH[4];
#pragma unroll
      for (int m = 0; m < 4; ++m) {
        const int r = wr + m * 16 + lr;
        aH[m] = *(const f16x8*)&sAh[r * 64 + (((ks * 4 + sl) ^ (r & 7)) * 8)];
      }
#pragma unroll
      for (int n = 0; n < 4; ++n) {
        const int r = wc + n * 16 + lr;
        bH[n] = *(const f16x8*)&sBh[r * 64 + (((ks * 4 + sl) ^ (r & 7)) * 8)];
      }
#pragma unroll
      for (int m = 0; m < 4; ++m)
#pragma unroll
        for (int n = 0; n < 4; ++n)
          acc[m][n] = __builtin_amdgcn_mfma_f32_16x16x32_f16(aH[m], bH[n],
                                                             acc[m][n], 0, 0, 0);
    }
    __syncthreads();
  }
  const int r4 = sl * 4;
#pragma unroll
  for (int m = 0; m < 4; ++m) {
#pragma unroll
    for (int r = 0; r < 4; ++r) {
      const int mm = bm + wr + m * 16 + r4 + r;
#pragma unroll
      for (int n = 0; n < 4; ++n) {
        const int col = bn + wc + n * 16 + lr;
        float v = acc[m][n][r] + bias[col];
        if (RELU) v = fmaxf(v, 0.f);
        if (PACK) ph[(size_t)mm * ldp + col] = f16b(v);
      }
    }
  }
}

// =========================================================================
// fp16 GEMM 128x64, templated BK (64 or 128). grid 768 = 3/CU balanced.
// RESM: 0 none, 1 f32 resid (rmod), 2 f16 resid. CSUM: column partials.
// =========================================================================
template <bool RELU, int RESM, bool PACK, bool CSUM, int BK>
__global__ __launch_bounds__(256, 3) void gemm_h64(
    const short* __restrict__ A, int lda, const short* __restrict__ Wt,
    int ldw, int Klen, const float* __restrict__ bias,
    const float* __restrict__ resid, const short* __restrict__ residS,
    int ldr, int rmod, short* __restrict__ ph, int ldp,
    float* __restrict__ part) {
  constexpr int GPR = BK / 8;
  constexpr int AR = 128 * GPR / 256;
  constexpr int BR = 64 * GPR / 256;
  constexpr int KS = BK / 32;
  __shared__ alignas(16) short sAh[128 * BK], sBh[64 * BK];
  __shared__ float csLds[2][64];
  const int tid = threadIdx.x;
  const unsigned Nt = gridDim.x;  // 8
  const unsigned lin = blockIdx.y * Nt + blockIdx.x;
  const unsigned cpx = (Nt * gridDim.y) >> 3;
  const unsigned swz = (lin & 7) * cpx + (lin >> 3);
  const int bn = (int)(swz % Nt) * 64, bmt = (int)(swz / Nt);
  const int bm = bmt * 128;
  const int wave = tid >> 6, lane = tid & 63;
  const int wr = (wave >> 1) * 64, wc = (wave & 1) * 32;
  const int lr = lane & 15, sl = lane >> 4;
  const short* Ab = A + (size_t)bm * lda;
  const short* Wb = Wt + (size_t)bn * ldw;
  f32x4 acc[4][2] = {};
  for (int kk = 0; kk < Klen; kk += BK) {
#pragma unroll
    for (int jj = 0; jj < AR; ++jj) {
      const int G = jj * 256 + tid;
      const int srow = G / GPR, sl0 = G % GPR;
      const int gsl = sl0 ^ (srow & (GPR - 1));
      gload16(Ab + (size_t)srow * lda + kk + gsl * 8, &sAh[G * 8]);
    }
#pragma unroll
    for (int jj = 0; jj < BR; ++jj) {
      const int G = jj * 256 + tid;
      const int srow = G / GPR, sl0 = G % GPR;
      const int gsl = sl0 ^ (srow & (GPR - 1));
      gload16(Wb + (size_t)srow * ldw + kk + gsl * 8, &sBh[G * 8]);
    }
    __syncthreads();
#pragma unroll
    for (int ks = 0; ks < KS; ++ks) {
      f16x8 aH[4], bH[2];
#pragma unroll
      for (int m = 0; m < 4; ++m) {
        const int r = wr + m * 16 + lr;
        aH[m] = *(const f16x8*)
            &sAh[r * BK + (((ks * 4 + sl) ^ (r & (GPR - 1))) * 8)];
      }
#pragma unroll
      for (int n = 0; n < 2; ++n) {
        const int r = wc + n * 16 + lr;
        bH[n] = *(const f16x8*)
            &sBh[r * BK + (((ks * 4 + sl) ^ (r & (GPR - 1))) * 8)];
      }
#pragma unroll
      for (int m = 0; m < 4; ++m)
#pragma unroll
        for (int n = 0; n < 2; ++n)
          acc[m][n] = __builtin_amdgcn_mfma_f32_16x16x32_f16(aH[m], bH[n],
                                                             acc[m][n], 0, 0, 0);
    }
    __syncthreads();
  }
  const int r4 = sl * 4;
  float cs[2] = {0.f, 0.f};
#pragma unroll
  for (int m = 0; m < 4; ++m) {
#pragma unroll
    for (int r = 0; r < 4; ++r) {
      const int mm = bm + wr + m * 16 + r4 + r;
#pragma unroll
      for (int n = 0; n < 2; ++n) {
        const int col = bn + wc + n * 16 + lr;
        float v = acc[m][n][r] + bias[col];
        if (RELU) v = fmaxf(v, 0.f);
        if (RESM == 1) {
          const int rr = rmod ? (mm % rmod) : mm;
          v += resid[(size_t)rr * ldr + col];
        }
        if (RESM == 2) v += h2f(residS[(size_t)mm * ldr + col]);
        if (PACK) ph[(size_t)mm * ldp + col] = f16b(v);
        if (CSUM) cs[n] += v;
      }
    }
  }
  if constexpr (CSUM) {
#pragma unroll
    for (int n = 0; n < 2; ++n) {
      cs[n] += __shfl_xor(cs[n], 16, 64);
      cs[n] += __shfl_xor(cs[n], 32, 64);
    }
    if (sl == 0) {
      csLds[wave >> 1][wc + lr] = cs[0];
      csLds[wave >> 1][wc + 16 + lr] = cs[1];
    }
    __syncthreads();
    if (tid < 64)
      part[(size_t)bmt * 512 + bn + tid] = csLds[0][tid] + csLds[1][tid];
  }
}

// =========================================================================
// Conv z-pair (ROUND-11 PROVEN FORM: BN=128, BK=64, dual f16 partials,
// grid 768 = 3/CU; 66.6 us/layer, MfmaUtil 36%, conflicts 0).
// Per zp block: side taps (t=-d,+d) for z=zp*2,zp*2+1 (alpha-scaled)
// + half the merged-center GEMM (W_mix has alpha baked in).
// =========================================================================
__global__ __launch_bounds__(256, 3) void conv_zp_k(
    const short* __restrict__ hp, const short* __restrict__ wt8,
    const short* __restrict__ wmix, const float* __restrict__ alpha,
    const short* __restrict__ zpadS, short* __restrict__ P) {
  __shared__ alignas(16) short sAh[8192], sBh[8192];
  const int tid = threadIdx.x;
  const unsigned lin = blockIdx.x;
  const unsigned swz = (lin & 7) * 96 + (lin >> 3);
  const int zp = (int)(swz / 384);
  const unsigned rem = swz % 384;
  const int bn = (int)(rem & 3) * 128;
  const int bmt = (int)(rem >> 2);
  const int b = bmt / 6, s0 = (bmt % 6) * 128, gm0 = bmt * 128;
  const int wave = tid >> 6, lane = tid & 63;
  const int wr = (wave >> 1) * 64, wc = (wave & 1) * 64;
  const int lr = lane & 15, sl = lane >> 4;
  const short* hb = hp + (size_t)b * S * 512;
  f32x4 accF[4][4] = {};
#pragma unroll
  for (int zi = 0; zi < 2; ++zi) {
    const int z = zp * 2 + zi;
    const int dd = 1 << z;
    f32x4 acc[4][4] = {};
    for (int kk = 0; kk < 1024; kk += 64) {
      const int tap = kk >> 9;  // 0: -d, 1: +d
      const int koff = kk & 511;
      const int off = tap ? dd : -dd;
#pragma unroll
      for (int jj = 0; jj < 4; ++jj) {
        const int G = jj * 256 + tid;
        const int srow = G >> 3, sl0 = G & 7;
        const int gsl = sl0 ^ (srow & 7);
        const int dst = G * 8;
        const int gs = s0 + srow + off;
        const bool inb = ((unsigned)gs < (unsigned)S);
        const short* aBase = hb + (size_t)gs * 512 + koff + gsl * 8;
        gload16(inb ? aBase : zpadS, &sAh[dst]);
        gload16(wt8 + ((size_t)((z * 2 + tap) * 512 + bn + srow)) * 512 +
                    koff + gsl * 8,
                &sBh[dst]);
      }
      __syncthreads();
#pragma unroll
      for (int ks = 0; ks < 2; ++ks) {
        f16x8 aH[4], bH[4];
#pragma unroll
        for (int m = 0; m < 4; ++m) {
          const int r = wr + m * 16 + lr;
          aH[m] =
              *(const f16x8*)&sAh[r * 64 + (((ks * 4 + sl) ^ (r & 7)) * 8)];
        }
#pragma unroll
        for (int n = 0; n < 4; ++n) {
          const int r = wc + n * 16 + lr;
          bH[n] =
              *(const f16x8*)&sBh[r * 64 + (((ks * 4 + sl) ^ (r & 7)) * 8)];
        }
#pragma unroll
        for (int m = 0; m < 4; ++m)
#pragma unroll
          for (int n = 0; n < 4; ++n)
            acc[m][n] = __builtin_amdgcn_mfma_f32_16x16x32_f16(
                aH[m], bH[n], acc[m][n], 0, 0, 0);
      }
      __syncthreads();
    }
    const float al = alpha[b * 4 + z];
#pragma unroll
    for (int m = 0; m < 4; ++m)
#pragma unroll
      for (int n = 0; n < 4; ++n)
#pragma unroll
        for (int r = 0; r < 4; ++r) accF[m][n][r] += al * acc[m][n][r];
  }
  // merged-center K-half (alpha baked into W_mix)
  const short* Wm = wmix + (size_t)b * 512 * 512;
  for (int kc = 0; kc < 256; kc += 64) {
    const int koff = zp * 256 + kc;
#pragma unroll
    for (int jj = 0; jj < 4; ++jj) {
      const int G = jj * 256 + tid;
      const int srow = G >> 3, sl0 = G & 7;
      const int gsl = sl0 ^ (srow & 7);
      const int dst = G * 8;
      gload16(hb + (size_t)(s0 + srow) * 512 + koff + gsl * 8, &sAh[dst]);
      gload16(Wm + (size_t)(bn + srow) * 512 + koff + gsl * 8, &sBh[dst]);
    }
    __syncthreads();
#pragma unroll
    for (int ks = 0; ks < 2; ++ks) {
      f16x8 aH[4], bH[4];
#pragma unroll
      for (int m = 0; m < 4; ++m) {
        const int r = wr + m * 16 + lr;
        aH[m] = *(const f16x8*)&sAh[r * 64 + (((ks * 4 + sl) ^ (r & 7)) * 8)];
      }
#pragma unroll
      for (int n = 0; n < 4; ++n) {
        const int r = wc + n * 16 + lr;
        bH[n] = *(const f16x8*)&sBh[r * 64 + (((ks * 4 + sl) ^ (r & 7)) * 8)];
      }
#pragma unroll
      for (int m = 0; m < 4; ++m)
#pragma unroll
        for (int n = 0; n < 4; ++n)
          accF[m][n] = __builtin_amdgcn_mfma_f32_16x16x32_f16(
              aH[m], bH[n], accF[m][n], 0, 0, 0);
    }
    __syncthreads();
  }
  short* Pz = P + (size_t)zp * ((size_t)BS * D);
  const int r4 = sl * 4;
#pragma unroll
  for (int m = 0; m < 4; ++m)
#pragma unroll
    for (int r = 0; r < 4; ++r) {
      const int mm = gm0 + wr + m * 16 + r4 + r;
#pragma unroll
      for (int n = 0; n < 4; ++n)
        Pz[(size_t)mm * D + bn + wc + n * 16 + lr] = f16b(accF[m][n][r]);
    }
}

// ---- fused conv-combine + LN1 -> LN2, all-f16 state (dual partial) -------
__global__ __launch_bounds__(256) void ln3_k(
    const short* __restrict__ P0, const short* __restrict__ P1,
    const short* __restrict__ hpk, const float* __restrict__ cbmix,
    const float* __restrict__ g1, const float* __restrict__ b1,
    const float* __restrict__ g2, const float* __restrict__ b2,
    short* __restrict__ pout) {
  const int row = blockIdx.x * 4 + (threadIdx.x >> 6);
  const int lane = threadIdx.x & 63;
  const int bb = row / S;
  const size_t base = (size_t)row * D;
  float v[8];
  float s = 0.f;
#pragma unroll
  for (int j = 0; j < 8; ++j) {
    const int c = lane + 64 * j;
    v[j] = h2f(P0[base + c]) + h2f(P1[base + c]) + h2f(hpk[base + c]) +
           cbmix[(size_t)bb * D + c];
    s += v[j];
  }
  s = wave_sum(s);
  const float m1 = s * (1.f / D);
  float q = 0.f;
#pragma unroll
  for (int j = 0; j < 8; ++j) { const float d = v[j] - m1; q += d * d; }
  q = wave_sum(q);
  const float r1 = rsqrtf(q * (1.f / D) + EPS);
  float y[8];
  float s2 = 0.f;
#pragma unroll
  for (int j = 0; j < 8; ++j) {
    const int c = lane + 64 * j;
    y[j] = (v[j] - m1) * r1 * g1[c] + b1[c];
    s2 += y[j];
  }
  s2 = wave_sum(s2);
  const float m2 = s2 * (1.f / D);
  float q2 = 0.f;
#pragma unroll
  for (int j = 0; j < 8; ++j) { const float d = y[j] - m2; q2 += d * d; }
  q2 = wave_sum(q2);
  const float r2 = rsqrtf(q2 * (1.f / D) + EPS);
  short* prow = pout + base;
#pragma unroll
  for (int j = 0; j < 8; ++j) {
    const int c = lane + 64 * j;
    prow[c] = f16b((y[j] - m2) * r2 * g2[c] + b2[c]);
  }
}

// ---- 64x64 transpose-pack tile body --------------------------------------
__device__ __forceinline__ void pack_tile(const float* __restrict__ W,
                                          short* __restrict__ out, int K,
                                          int N, int n0, int k0) {
  __shared__ short t[64][68];
  const int ln = threadIdx.x & 63, w4 = threadIdx.x >> 6;
#pragma unroll
  for (int it = 0; it < 16; ++it) {
    const int kr = it * 4 + w4;
    t[kr][ln] = f16b(W[(size_t)(k0 + kr) * N + n0 + ln]);
  }
  __syncthreads();
#pragma unroll
  for (int it = 0; it < 16; ++it) {
    const int nr = it * 4 + w4;
    out[(size_t)(n0 + nr) * K + k0 + ln] = t[ln][nr];
  }
}

// ---- W transpose-pack: (K,N) f32 -> (N,K) fp16 ---------------------------
__global__ __launch_bounds__(256) void pack_wt_k(const float* __restrict__ W,
                                                 short* __restrict__ out,
                                                 int K, int N) {
  pack_tile(W, out, K, N, blockIdx.x * 64, blockIdx.y * 64);
}

// ---- all-FF pack: 12 weights (6 x {ffw1, ffw2}), 3072 blocks -------------
__global__ __launch_bounds__(256) void pack_ff_all_k(
    const float* __restrict__ ffw1, const float* __restrict__ ffw2,
    short* __restrict__ outAll) {
  const int bid = blockIdx.x;
  const int l = bid >> 9;
  const int r = bid & 511;
  if (r < 256) {
    pack_tile(ffw1 + (size_t)l * D * FF, outAll + (size_t)l * 2097152, 512,
              2048, (r & 31) * 64, (r >> 5) * 64);
  } else {
    const int r2 = r - 256;
    pack_tile(ffw2 + (size_t)l * FF * D,
              outAll + (size_t)l * 2097152 + 1048576, 2048, 512,
              (r2 & 7) * 64, (r2 >> 3) * 64);
  }
}

// ---- all conv side-tap pack: (L,4,O,I,3) taps {0,2} -> (L,8,O,I) ---------
__global__ __launch_bounds__(256) void pack_conv8_all_k(
    const float* __restrict__ cw, short* __restrict__ out) {
  const size_t idx = (size_t)blockIdx.x * 256 + threadIdx.x;  // 6*8*512*512
  const int c = (int)(idx & 511);
  const int o = (int)((idx >> 9) & 511);
  const int seg = (int)((idx >> 18) & 7);
  const int l = (int)(idx >> 21);
  const int z = seg >> 1, t = (seg & 1) * 2;
  out[idx] =
      f16b(cw[((size_t)l * 4 * D * D + ((size_t)z * D + o) * D + c) * 3 + t]);
}

// ---- W_mix[b] = sum_z alpha[b,z] * W[z,center]  (f32 mix -> fp16) --------
__global__ __launch_bounds__(256) void wmix_k(const float* __restrict__ cw,
                                              const float* __restrict__ alpha,
                                              short* __restrict__ wm) {
  __shared__ float sal[64];
  if (threadIdx.x < 64) sal[threadIdx.x] = alpha[threadIdx.x];
  __syncthreads();
  const int idx = blockIdx.x * 256 + threadIdx.x;  // 262144 (o,c)
  const int c = idx & 511, o = idx >> 9;
  float w[4];
#pragma unroll
  for (int z = 0; z < 4; ++z)
    w[z] = cw[(((size_t)z * D + o) * D + c) * 3 + 1];
#pragma unroll
  for (int b = 0; b < 16; ++b) {
    const float v = sal[b * 4 + 0] * w[0] + sal[b * 4 + 1] * w[1] +
                    sal[b * 4 + 2] * w[2] + sal[b * 4 + 3] * w[3];
    wm[((size_t)b * D + o) * D + c] = f16b(v);
  }
}

__global__ __launch_bounds__(256) void zero_k(float* __restrict__ p) {
  p[threadIdx.x] = 0.f;
  p[threadIdx.x + 256] = 0.f;
}

// ---- alpha from GEMM column partials; cb_mix[b] = sum a_z cb_z -----------
__global__ __launch_bounds__(64) void alpha_k(const float* __restrict__ part,
                                              const float* __restrict__ wmw,
                                              const float* __restrict__ wmb,
                                              const float* __restrict__ cb,
                                              float* __restrict__ alpha,
                                              float* __restrict__ cbmix) {
  const int b = blockIdx.x, t = threadIdx.x;
  float p0 = 0, p1 = 0, p2 = 0, p3 = 0;
  for (int d = t; d < D; d += 64) {
    float xm = 0;
#pragma unroll
    for (int c = 0; c < 6; ++c) xm += part[((size_t)(b * 6 + c)) * D + d];
    xm *= (1.f / S);
    p0 += xm * wmw[d * 4 + 0];
    p1 += xm * wmw[d * 4 + 1];
    p2 += xm * wmw[d * 4 + 2];
    p3 += xm * wmw[d * 4 + 3];
  }
  p0 = wave_sum(p0); p1 = wave_sum(p1);
  p2 = wave_sum(p2); p3 = wave_sum(p3);
  const float l0 = p0 + wmb[0], l1 = p1 + wmb[1];
  const float l2 = p2 + wmb[2], l3 = p3 + wmb[3];
  const float mx = fmaxf(fmaxf(l0, l1), fmaxf(l2, l3));
  const float e0 = expf(l0 - mx), e1 = expf(l1 - mx);
  const float e2 = expf(l2 - mx), e3 = expf(l3 - mx);
  const float inv = 1.f / (e0 + e1 + e2 + e3);
  const float a0 = e0 * inv, a1 = e1 * inv, a2 = e2 * inv, a3 = e3 * inv;
  if (t == 0) {
    alpha[b * 4 + 0] = a0;
    alpha[b * 4 + 1] = a1;
    alpha[b * 4 + 2] = a2;
    alpha[b * 4 + 3] = a3;
  }
  for (int c = t; c < D; c += 64)
    cbmix[(size_t)b * D + c] =
        a0 * cb[c] + a1 * cb[D + c] + a2 * cb[2 * D + c] + a3 * cb[3 * D + c];
}

// ---- embedding gather-mean, hi-pack out ----------------------------------
__global__ __launch_bounds__(256) void embed_k(const int* __restrict__ xe,
                                               const float* __restrict__ emb,
                                               short* __restrict__ out) {
  const int r = blockIdx.x;
  int idx[8];
#pragma unroll
  for (int j = 0; j < 8; ++j) idx[j] = xe[r * 8 + j];
  short* o = out + (size_t)r * 512;
  for (int d = threadIdx.x; d < D; d += 256) {
    float s = 0.f;
#pragma unroll
    for (int j = 0; j < 8; ++j) s += emb[(size_t)idx[j] * D + d];
    o[d] = f16b(s * 0.125f);
  }
}

// ---- L2-normalize rows of (BS,64), hi-pack out ---------------------------
__global__ __launch_bounds__(256) void norml2_k(const float* __restrict__ x,
                                                short* __restrict__ out) {
  const int r = blockIdx.x * 4 + (threadIdx.x >> 6);
  const int lane = threadIdx.x & 63;
  const float v = x[(size_t)r * 64 + lane];
  const float s = wave_sum(v * v);
  const float nrm = fmaxf(sqrtf(s), 1e-12f);
  out[(size_t)r * 64 + lane] = f16b(v / nrm);
}

// ---- classifier head (reads GEMM column partials) ------------------------
__global__ __launch_bounds__(256) void head_k(
    const float* __restrict__ part, const float* __restrict__ pw1,
    const float* __restrict__ pb1, const float* __restrict__ pw2,
    const float* __restrict__ pb2, float* __restrict__ out) {
  __shared__ float hg[D];
  __shared__ float red[256];
  const int b = blockIdx.x, t = threadIdx.x;
  for (int d = t; d < D; d += 256) {
    float s = 0.f;
#pragma unroll
    for (int c = 0; c < 6; ++c) s += part[((size_t)(b * 6 + c)) * D + d];
    hg[d] = s * (1.f / S);
  }
  __syncthreads();
  float s = pb1[t];
  for (int d = 0; d < D; ++d) s = fmaf(hg[d], pw1[(size_t)d * 256 + t], s);
  s = fmaxf(s, 0.f);
  red[t] = s * pw2[t];
  __syncthreads();
  for (int o = 128; o > 0; o >>= 1) {
    if (t < o) red[t] += red[t + o];
    __syncthreads();
  }
  if (t == 0) out[b] = red[0] + pb2[0];
}

}  // namespace

extern "C" void kernel_launch(void* const* d_in, const int* in_sizes, int n_in,
                              void* d_out, int out_size, void* d_ws,
                              size_t ws_size, hipStream_t stream) {
  const float* x_cog = (const float*)d_in[0];
  const float* cw1 = (const float*)d_in[1];
  const float* cb1 = (const float*)d_in[2];
  const float* cw2 = (const float*)d_in[3];
  const float* cb2 = (const float*)d_in[4];
  const float* env_emb = (const float*)d_in[5];
  const float* ew1 = (const float*)d_in[6];
  const float* eb1 = (const float*)d_in[7];
  const float* ew2 = (const float*)d_in[8];
  const float* eb2 = (const float*)d_in[9];
  const float* fw1 = (const float*)d_in[10];
  const float* fb1 = (const float*)d_in[11];
  const float* fw2 = (const float*)d_in[12];
  const float* fb2 = (const float*)d_in[13];
  const float* pos_enc = (const float*)d_in[14];
  const float* conv_w = (const float*)d_in[15];
  const float* conv_b = (const float*)d_in[16];
  const float* wm_w = (const float*)d_in[17];
  const float* wm_b = (const float*)d_in[18];
  // d_in[19..21] = ssm_w/ssm_b/A_log: no-ops (y scalar-per-row cancels in LN2)
  const float* ffw1 = (const float*)d_in[22];
  const float* ffb1 = (const float*)d_in[23];
  const float* ffw2 = (const float*)d_in[24];
  const float* ffb2 = (const float*)d_in[25];
  const float* g1 = (const float*)d_in[26];
  const float* be1 = (const float*)d_in[27];
  const float* g2 = (const float*)d_in[28];
  const float* be2 = (const float*)d_in[29];
  const float* pw1 = (const float*)d_in[30];
  const float* pb1 = (const float*)d_in[31];
  const float* pw2 = (const float*)d_in[32];
  const float* pb2 = (const float*)d_in[33];
  const int* x_env = (const int*)d_in[34];
  float* out = (float*)d_out;

  // ---- arena (~173 MB) ----------------------------------------------------
  float* ws = (float*)d_ws;
  float* PART2 = ws;                       // 96x512 f32
  float* ALPHAB = PART2 + 65536;           // 64
  float* ZPADF = ALPHAB + 64;              // 512 zero page
  float* CBMIX = ZPADF + 512;              // 16x512 f32
  short* R = (short*)(CBMIX + 8192);
  short* WFFALL = R;                       // 6x2x1,048,576 [0, 12,582,912)
  short* WC8ALL = R + 12582912;            // 6x8x512x512   [12,582,912, 25,165,824)
  short* WMIX = R + 25165824;              // 16x512x512    [25,165,824, 29,360,128)
  short* convPh = R + 29360128;            // 2x12288x512   [29,360,128, 41,943,040)
  short* HPACK = R + 41943040;             // 12288x512     [41,943,040, 48,234,496)
  short* APFF = R + 48234496;              // 12288x2048    [48,234,496, 73,400,320)
  short* CONC = APFF;                      // frontend alias (CONC dead before
                                           // APFF first written in layer 0)
  short* PK1 = R + 73400320;               // 12288x512
  short* PK2 = R + 79691776;               // 12288x512
  short* WPBF = R + 85983232;              // frontend W pack (<=524,288)

  const dim3 blk(256);
  const dim3 gS(8, 96, 1);    // N=512, BN=64 -> 768 blocks (3/CU)
  const dim3 gF(16, 96, 1);   // N=2048, BN=128 -> 1536 blocks

  zero_k<<<1, blk, 0, stream>>>(ZPADF);
  pack_ff_all_k<<<3072, blk, 0, stream>>>(ffw1, ffw2, WFFALL);
  pack_conv8_all_k<<<49152, blk, 0, stream>>>(conv_w, WC8ALL);

  // ---- frontend -----------------------------------------------------------
  norml2_k<<<BS / 4, blk, 0, stream>>>(x_cog, PK1);
  pack_wt_k<<<dim3(8, 1), blk, 0, stream>>>(cw1, WPBF, 64, 512);
  gemm_h64<true, 0, true, false, 64><<<gS, blk, 0, stream>>>(
      PK1, 64, WPBF, 64, 64, cb1, nullptr, nullptr, 0, 0, PK2, 512, nullptr);
  pack_wt_k<<<dim3(8, 8), blk, 0, stream>>>(cw2, WPBF, 512, 512);
  gemm_h64<false, 0, true, false, 128><<<gS, blk, 0, stream>>>(
      PK2, 512, WPBF, 512, 512, cb2, nullptr, nullptr, 0, 0, CONC, 2048,
      nullptr);
  embed_k<<<BS, blk, 0, stream>>>(x_env, env_emb, PK1);
  pack_wt_k<<<dim3(8, 8), blk, 0, stream>>>(ew1, WPBF, 512, 512);
  gemm_h64<true, 0, true, false, 128><<<gS, blk, 0, stream>>>(
      PK1, 512, WPBF, 512, 512, eb1, nullptr, nullptr, 0, 0, PK2, 512,
      nullptr);
  pack_wt_k<<<dim3(8, 8), blk, 0, stream>>>(ew2, WPBF, 512, 512);
  gemm_h64<false, 0, true, false, 128><<<gS, blk, 0, stream>>>(
      PK2, 512, WPBF, 512, 512, eb2, nullptr, nullptr, 0, 0, CONC + 512, 2048,
      nullptr);
  pack_wt_k<<<dim3(8, 16), blk, 0, stream>>>(fw1, WPBF, 1024, 512);
  gemm_h64<true, 0, true, false, 128><<<gS, blk, 0, stream>>>(
      CONC, 2048, WPBF, 1024, 1024, fb1, nullptr, nullptr, 0, 0, PK1, 512,
      nullptr);
  pack_wt_k<<<dim3(8, 8), blk, 0, stream>>>(fw2, WPBF, 512, 512);
  // h = (PK1@fw2 + fb2) + pos_enc -> HPACK hi + PART2 colsums
  gemm_h64<false, 1, true, true, 128><<<gS, blk, 0, stream>>>(
      PK1, 512, WPBF, 512, 512, fb2, pos_enc, nullptr, 512, S, HPACK, 512,
      PART2);

  // ---- layers (all-f16 state, 6 dispatches each) -------------------------
  for (int l = 0; l < L; ++l) {
    const float* cwl = conv_w + (size_t)l * 4 * D * D * 3;
    alpha_k<<<B, dim3(64), 0, stream>>>(PART2, wm_w + (size_t)l * D * 4,
                                        wm_b + l * 4,
                                        conv_b + (size_t)l * 4 * D, ALPHAB,
                                        CBMIX);
    wmix_k<<<1024, blk, 0, stream>>>(cwl, ALPHAB, WMIX);
    conv_zp_k<<<768, blk, 0, stream>>>(HPACK, WC8ALL + (size_t)l * 2097152,
                                       WMIX, ALPHAB, (const short*)ZPADF,
                                       convPh);
    // h2 = LN2(LN1(P0+P1+h+cb_mix)) -> HPACK (in-place h -> h2)
    ln3_k<<<BS / 4, blk, 0, stream>>>(convPh, convPh + (size_t)BS * D, HPACK,
                                      CBMIX, g1 + l * D, be1 + l * D,
                                      g2 + l * D, be2 + l * D, HPACK);
    gemm_h<true, true><<<gF, blk, 0, stream>>>(
        HPACK, 512, WFFALL + (size_t)l * 2097152, 512, 512,
        ffb1 + (size_t)l * FF, APFF, 2048);
    // new h = APFF@ffw2 + ffb2 + h2(f16) -> HPACK (in-place) + PART2 colsums
    gemm_h64<false, 2, true, true, 128><<<gS, blk, 0, stream>>>(
        APFF, 2048, WFFALL + (size_t)l * 2097152 + 1048576, 2048, 2048,
        ffb2 + (size_t)l * D, nullptr, HPACK, 512, 0, HPACK, 512, PART2);
  }

  // ---- head ---------------------------------------------------------------
  head_k<<<B, blk, 0, stream>>>(PART2, pw1, pb1, pw2, pb2, out);
}

// Round 14
// 1133.220 us; speedup vs baseline: 1.0985x; 1.0086x over previous
//
#include <hip/hip_runtime.h>
#include <cstdint>
#include <cstddef>

namespace {

constexpr int B = 16, S = 768, BS = B * S, D = 512, FF = 2048, L = 6;
constexpr float EPS = 1e-5f;

typedef float f32x4 __attribute__((ext_vector_type(4)));
typedef _Float16 f16x8 __attribute__((ext_vector_type(8)));

__device__ __forceinline__ float wave_sum(float v) {
#pragma unroll
  for (int o = 32; o > 0; o >>= 1) v += __shfl_xor(v, o, 64);
  return v;
}

__device__ __forceinline__ short f16b(float x) {
  const _Float16 h = (_Float16)x;
  return __builtin_bit_cast(short, h);
}
__device__ __forceinline__ float h2f(short s) {
  return (float)__builtin_bit_cast(_Float16, s);
}

// ---- async global->LDS, 16B per lane ------------------------------------
__device__ __forceinline__ void gload16(const void* g, void* l) {
  __builtin_amdgcn_global_load_lds(
      (const __attribute__((address_space(1))) void*)g,
      (__attribute__((address_space(3))) void*)l, 16, 0, 0);
}

// LDS tile [rows][BK/8 slots of 16B]. Bank fix: global slot gsl = sl0 ^
// (row & (SLOTS-1)); LDS linear (rule #21). 2-way residual = free (m136).

// =========================================================================
// fp16 GEMM 128x128, BK=64 (FF1, N=2048: grid 1536, balanced).
// =========================================================================
template <bool RELU, bool PACK>
__global__ __launch_bounds__(256, 3) void gemm_h(
    const short* __restrict__ A, int lda, const short* __restrict__ Wt,
    int ldw, int Klen, const float* __restrict__ bias,
    short* __restrict__ ph, int ldp) {
  __shared__ alignas(16) short sAh[8192], sBh[8192];
  const int tid = threadIdx.x;
  const unsigned Nt = gridDim.x;
  const unsigned lin = blockIdx.y * Nt + blockIdx.x;
  const unsigned cpx = (Nt * gridDim.y) >> 3;
  const unsigned swz = (lin & 7) * cpx + (lin >> 3);
  const int bn = (int)(swz % Nt) * 128, bm = (int)(swz / Nt) * 128;
  const int wave = tid >> 6, lane = tid & 63;
  const int wr = (wave >> 1) * 64, wc = (wave & 1) * 64;
  const int lr = lane & 15, sl = lane >> 4;
  const short* Ab = A + (size_t)bm * lda;
  const short* Wb = Wt + (size_t)bn * ldw;
  f32x4 acc[4][4] = {};
  for (int kk = 0; kk < Klen; kk += 64) {
#pragma unroll
    for (int jj = 0; jj < 4; ++jj) {
      const int G = jj * 256 + tid;
      const int srow = G >> 3, sl0 = G & 7;
      const int gsl = sl0 ^ (srow & 7);
      const int dst = G * 8;
      gload16(Ab + (size_t)srow * lda + kk + gsl * 8, &sAh[dst]);
      gload16(Wb + (size_t)srow * ldw + kk + gsl * 8, &sBh[dst]);
    }
    __syncthreads();
#pragma unroll
    for (int ks = 0; ks < 2; ++ks) {
      f16x8 aH[4], bH[4];
#pragma unroll
      for (int m = 0; m < 4; ++m) {
        const int r = wr + m * 16 + lr;
        aH[m] = *(const f16x8*)&sAh[r * 64 + (((ks * 4 + sl) ^ (r & 7)) * 8)];
      }
#pragma unroll
      for (int n = 0; n < 4; ++n) {
        const int r = wc + n * 16 + lr;
        bH[n] = *(const f16x8*)&sBh[r * 64 + (((ks * 4 + sl) ^ (r & 7)) * 8)];
      }
#pragma unroll
      for (int m = 0; m < 4; ++m)
#pragma unroll
        for (int n = 0; n < 4; ++n)
          acc[m][n] = __builtin_amdgcn_mfma_f32_16x16x32_f16(aH[m], bH[n],
                                                             acc[m][n], 0, 0, 0);
    }
    __syncthreads();
  }
  const int r4 = sl * 4;
#pragma unroll
  for (int m = 0; m < 4; ++m) {
#pragma unroll
    for (int r = 0; r < 4; ++r) {
      const int mm = bm + wr + m * 16 + r4 + r;
#pragma unroll
      for (int n = 0; n < 4; ++n) {
        const int col = bn + wc + n * 16 + lr;
        float v = acc[m][n][r] + bias[col];
        if (RELU) v = fmaxf(v, 0.f);
        if (PACK) ph[(size_t)mm * ldp + col] = f16b(v);
      }
    }
  }
}

// =========================================================================
// fp16 GEMM 128x64, BK=64 (round-11 proven). grid 768 = 3/CU balanced.
// RESM: 0 none, 1 f32 resid (rmod), 2 f16 resid. CSUM: column partials.
// =========================================================================
template <bool RELU, int RESM, bool PACK, bool CSUM>
__global__ __launch_bounds__(256, 3) void gemm_h64(
    const short* __restrict__ A, int lda, const short* __restrict__ Wt,
    int ldw, int Klen, const float* __restrict__ bias,
    const float* __restrict__ resid, const short* __restrict__ residS,
    int ldr, int rmod, short* __restrict__ ph, int ldp,
    float* __restrict__ part) {
  __shared__ alignas(16) short sAh[8192], sBh[4096];
  __shared__ float csLds[2][64];
  const int tid = threadIdx.x;
  const unsigned Nt = gridDim.x;  // 8
  const unsigned lin = blockIdx.y * Nt + blockIdx.x;
  const unsigned cpx = (Nt * gridDim.y) >> 3;
  const unsigned swz = (lin & 7) * cpx + (lin >> 3);
  const int bn = (int)(swz % Nt) * 64, bmt = (int)(swz / Nt);
  const int bm = bmt * 128;
  const int wave = tid >> 6, lane = tid & 63;
  const int wr = (wave >> 1) * 64, wc = (wave & 1) * 32;
  const int lr = lane & 15, sl = lane >> 4;
  const short* Ab = A + (size_t)bm * lda;
  const short* Wb = Wt + (size_t)bn * ldw;
  f32x4 acc[4][2] = {};
  for (int kk = 0; kk < Klen; kk += 64) {
#pragma unroll
    for (int jj = 0; jj < 4; ++jj) {
      const int G = jj * 256 + tid;
      const int srow = G >> 3, sl0 = G & 7;
      const int gsl = sl0 ^ (srow & 7);
      gload16(Ab + (size_t)srow * lda + kk + gsl * 8, &sAh[G * 8]);
    }
#pragma unroll
    for (int jj = 0; jj < 2; ++jj) {
      const int G = jj * 256 + tid;
      const int srow = G >> 3, sl0 = G & 7;
      const int gsl = sl0 ^ (srow & 7);
      gload16(Wb + (size_t)srow * ldw + kk + gsl * 8, &sBh[G * 8]);
    }
    __syncthreads();
#pragma unroll
    for (int ks = 0; ks < 2; ++ks) {
      f16x8 aH[4], bH[2];
#pragma unroll
      for (int m = 0; m < 4; ++m) {
        const int r = wr + m * 16 + lr;
        aH[m] = *(const f16x8*)&sAh[r * 64 + (((ks * 4 + sl) ^ (r & 7)) * 8)];
      }
#pragma unroll
      for (int n = 0; n < 2; ++n) {
        const int r = wc + n * 16 + lr;
        bH[n] = *(const f16x8*)&sBh[r * 64 + (((ks * 4 + sl) ^ (r & 7)) * 8)];
      }
#pragma unroll
      for (int m = 0; m < 4; ++m)
#pragma unroll
        for (int n = 0; n < 2; ++n)
          acc[m][n] = __builtin_amdgcn_mfma_f32_16x16x32_f16(aH[m], bH[n],
                                                             acc[m][n], 0, 0, 0);
    }
    __syncthreads();
  }
  const int r4 = sl * 4;
  float cs[2] = {0.f, 0.f};
#pragma unroll
  for (int m = 0; m < 4; ++m) {
#pragma unroll
    for (int r = 0; r < 4; ++r) {
      const int mm = bm + wr + m * 16 + r4 + r;
#pragma unroll
      for (int n = 0; n < 2; ++n) {
        const int col = bn + wc + n * 16 + lr;
        float v = acc[m][n][r] + bias[col];
        if (RELU) v = fmaxf(v, 0.f);
        if (RESM == 1) {
          const int rr = rmod ? (mm % rmod) : mm;
          v += resid[(size_t)rr * ldr + col];
        }
        if (RESM == 2) v += h2f(residS[(size_t)mm * ldr + col]);
        if (PACK) ph[(size_t)mm * ldp + col] = f16b(v);
        if (CSUM) cs[n] += v;
      }
    }
  }
  if constexpr (CSUM) {
#pragma unroll
    for (int n = 0; n < 2; ++n) {
      cs[n] += __shfl_xor(cs[n], 16, 64);
      cs[n] += __shfl_xor(cs[n], 32, 64);
    }
    if (sl == 0) {
      csLds[wave >> 1][wc + lr] = cs[0];
      csLds[wave >> 1][wc + 16 + lr] = cs[1];
    }
    __syncthreads();
    if (tid < 64)
      part[(size_t)bmt * 512 + bn + tid] = csLds[0][tid] + csLds[1][tid];
  }
}

// =========================================================================
// Conv z-pair (round-11 proven: BN=128, BK=64, dual f16 partials,
// grid 768 = 3/CU; ~67 us/layer, MfmaUtil ~35%, conflicts 0).
// =========================================================================
__global__ __launch_bounds__(256, 3) void conv_zp_k(
    const short* __restrict__ hp, const short* __restrict__ wt8,
    const short* __restrict__ wmix, const float* __restrict__ alpha,
    const short* __restrict__ zpadS, short* __restrict__ P) {
  __shared__ alignas(16) short sAh[8192], sBh[8192];
  const int tid = threadIdx.x;
  const unsigned lin = blockIdx.x;
  const unsigned swz = (lin & 7) * 96 + (lin >> 3);
  const int zp = (int)(swz / 384);
  const unsigned rem = swz % 384;
  const int bn = (int)(rem & 3) * 128;
  const int bmt = (int)(rem >> 2);
  const int b = bmt / 6, s0 = (bmt % 6) * 128, gm0 = bmt * 128;
  const int wave = tid >> 6, lane = tid & 63;
  const int wr = (wave >> 1) * 64, wc = (wave & 1) * 64;
  const int lr = lane & 15, sl = lane >> 4;
  const short* hb = hp + (size_t)b * S * 512;
  f32x4 accF[4][4] = {};
#pragma unroll
  for (int zi = 0; zi < 2; ++zi) {
    const int z = zp * 2 + zi;
    const int dd = 1 << z;
    f32x4 acc[4][4] = {};
    for (int kk = 0; kk < 1024; kk += 64) {
      const int tap = kk >> 9;  // 0: -d, 1: +d
      const int koff = kk & 511;
      const int off = tap ? dd : -dd;
#pragma unroll
      for (int jj = 0; jj < 4; ++jj) {
        const int G = jj * 256 + tid;
        const int srow = G >> 3, sl0 = G & 7;
        const int gsl = sl0 ^ (srow & 7);
        const int dst = G * 8;
        const int gs = s0 + srow + off;
        const bool inb = ((unsigned)gs < (unsigned)S);
        const short* aBase = hb + (size_t)gs * 512 + koff + gsl * 8;
        gload16(inb ? aBase : zpadS, &sAh[dst]);
        gload16(wt8 + ((size_t)((z * 2 + tap) * 512 + bn + srow)) * 512 +
                    koff + gsl * 8,
                &sBh[dst]);
      }
      __syncthreads();
#pragma unroll
      for (int ks = 0; ks < 2; ++ks) {
        f16x8 aH[4], bH[4];
#pragma unroll
        for (int m = 0; m < 4; ++m) {
          const int r = wr + m * 16 + lr;
          aH[m] =
              *(const f16x8*)&sAh[r * 64 + (((ks * 4 + sl) ^ (r & 7)) * 8)];
        }
#pragma unroll
        for (int n = 0; n < 4; ++n) {
          const int r = wc + n * 16 + lr;
          bH[n] =
              *(const f16x8*)&sBh[r * 64 + (((ks * 4 + sl) ^ (r & 7)) * 8)];
        }
#pragma unroll
        for (int m = 0; m < 4; ++m)
#pragma unroll
          for (int n = 0; n < 4; ++n)
            acc[m][n] = __builtin_amdgcn_mfma_f32_16x16x32_f16(
                aH[m], bH[n], acc[m][n], 0, 0, 0);
      }
      __syncthreads();
    }
    const float al = alpha[b * 4 + z];
#pragma unroll
    for (int m = 0; m < 4; ++m)
#pragma unroll
      for (int n = 0; n < 4; ++n)
#pragma unroll
        for (int r = 0; r < 4; ++r) accF[m][n][r] += al * acc[m][n][r];
  }
  // merged-center K-half (alpha baked into W_mix)
  const short* Wm = wmix + (size_t)b * 512 * 512;
  for (int kc = 0; kc < 256; kc += 64) {
    const int koff = zp * 256 + kc;
#pragma unroll
    for (int jj = 0; jj < 4; ++jj) {
      const int G = jj * 256 + tid;
      const int srow = G >> 3, sl0 = G & 7;
      const int gsl = sl0 ^ (srow & 7);
      const int dst = G * 8;
      gload16(hb + (size_t)(s0 + srow) * 512 + koff + gsl * 8, &sAh[dst]);
      gload16(Wm + (size_t)(bn + srow) * 512 + koff + gsl * 8, &sBh[dst]);
    }
    __syncthreads();
#pragma unroll
    for (int ks = 0; ks < 2; ++ks) {
      f16x8 aH[4], bH[4];
#pragma unroll
      for (int m = 0; m < 4; ++m) {
        const int r = wr + m * 16 + lr;
        aH[m] = *(const f16x8*)&sAh[r * 64 + (((ks * 4 + sl) ^ (r & 7)) * 8)];
      }
#pragma unroll
      for (int n = 0; n < 4; ++n) {
        const int r = wc + n * 16 + lr;
        bH[n] = *(const f16x8*)&sBh[r * 64 + (((ks * 4 + sl) ^ (r & 7)) * 8)];
      }
#pragma unroll
      for (int m = 0; m < 4; ++m)
#pragma unroll
        for (int n = 0; n < 4; ++n)
          accF[m][n] = __builtin_amdgcn_mfma_f32_16x16x32_f16(
              aH[m], bH[n], accF[m][n], 0, 0, 0);
    }
    __syncthreads();
  }
  short* Pz = P + (size_t)zp * ((size_t)BS * D);
  const int r4 = sl * 4;
#pragma unroll
  for (int m = 0; m < 4; ++m)
#pragma unroll
    for (int r = 0; r < 4; ++r) {
      const int mm = gm0 + wr + m * 16 + r4 + r;
#pragma unroll
      for (int n = 0; n < 4; ++n)
        Pz[(size_t)mm * D + bn + wc + n * 16 + lr] = f16b(accF[m][n][r]);
    }
}

// ---- fused conv-combine + LN1 -> LN2, all-f16 state (dual partial) -------
__global__ __launch_bounds__(256) void ln3_k(
    const short* __restrict__ P0, const short* __restrict__ P1,
    const short* __restrict__ hpk, const float* __restrict__ cbmix,
    const float* __restrict__ g1, const float* __restrict__ b1,
    const float* __restrict__ g2, const float* __restrict__ b2,
    short* __restrict__ pout) {
  const int row = blockIdx.x * 4 + (threadIdx.x >> 6);
  const int lane = threadIdx.x & 63;
  const int bb = row / S;
  const size_t base = (size_t)row * D;
  float v[8];
  float s = 0.f;
#pragma unroll
  for (int j = 0; j < 8; ++j) {
    const int c = lane + 64 * j;
    v[j] = h2f(P0[base + c]) + h2f(P1[base + c]) + h2f(hpk[base + c]) +
           cbmix[(size_t)bb * D + c];
    s += v[j];
  }
  s = wave_sum(s);
  const float m1 = s * (1.f / D);
  float q = 0.f;
#pragma unroll
  for (int j = 0; j < 8; ++j) { const float d = v[j] - m1; q += d * d; }
  q = wave_sum(q);
  const float r1 = rsqrtf(q * (1.f / D) + EPS);
  float y[8];
  float s2 = 0.f;
#pragma unroll
  for (int j = 0; j < 8; ++j) {
    const int c = lane + 64 * j;
    y[j] = (v[j] - m1) * r1 * g1[c] + b1[c];
    s2 += y[j];
  }
  s2 = wave_sum(s2);
  const float m2 = s2 * (1.f / D);
  float q2 = 0.f;
#pragma unroll
  for (int j = 0; j < 8; ++j) { const float d = y[j] - m2; q2 += d * d; }
  q2 = wave_sum(q2);
  const float r2 = rsqrtf(q2 * (1.f / D) + EPS);
  short* prow = pout + base;
#pragma unroll
  for (int j = 0; j < 8; ++j) {
    const int c = lane + 64 * j;
    prow[c] = f16b((y[j] - m2) * r2 * g2[c] + b2[c]);
  }
}

// ---- 64x64 transpose-pack tile body --------------------------------------
__device__ __forceinline__ void pack_tile(const float* __restrict__ W,
                                          short* __restrict__ out, int K,
                                          int N, int n0, int k0) {
  __shared__ short t[64][68];
  const int ln = threadIdx.x & 63, w4 = threadIdx.x >> 6;
#pragma unroll
  for (int it = 0; it < 16; ++it) {
    const int kr = it * 4 + w4;
    t[kr][ln] = f16b(W[(size_t)(k0 + kr) * N + n0 + ln]);
  }
  __syncthreads();
#pragma unroll
  for (int it = 0; it < 16; ++it) {
    const int nr = it * 4 + w4;
    out[(size_t)(n0 + nr) * K + k0 + ln] = t[ln][nr];
  }
}

// ---- W transpose-pack: (K,N) f32 -> (N,K) fp16 ---------------------------
__global__ __launch_bounds__(256) void pack_wt_k(const float* __restrict__ W,
                                                 short* __restrict__ out,
                                                 int K, int N) {
  pack_tile(W, out, K, N, blockIdx.x * 64, blockIdx.y * 64);
}

// ---- all-FF pack: 12 weights (6 x {ffw1, ffw2}), 3072 blocks -------------
__global__ __launch_bounds__(256) void pack_ff_all_k(
    const float* __restrict__ ffw1, const float* __restrict__ ffw2,
    short* __restrict__ outAll) {
  const int bid = blockIdx.x;
  const int l = bid >> 9;
  const int r = bid & 511;
  if (r < 256) {
    pack_tile(ffw1 + (size_t)l * D * FF, outAll + (size_t)l * 2097152, 512,
              2048, (r & 31) * 64, (r >> 5) * 64);
  } else {
    const int r2 = r - 256;
    pack_tile(ffw2 + (size_t)l * FF * D,
              outAll + (size_t)l * 2097152 + 1048576, 2048, 512,
              (r2 & 7) * 64, (r2 >> 3) * 64);
  }
}

// ---- all conv side-tap pack: (L,4,O,I,3) taps {0,2} -> (L,8,O,I) ---------
__global__ __launch_bounds__(256) void pack_conv8_all_k(
    const float* __restrict__ cw, short* __restrict__ out) {
  const size_t idx = (size_t)blockIdx.x * 256 + threadIdx.x;  // 6*8*512*512
  const int c = (int)(idx & 511);
  const int o = (int)((idx >> 9) & 511);
  const int seg = (int)((idx >> 18) & 7);
  const int l = (int)(idx >> 21);
  const int z = seg >> 1, t = (seg & 1) * 2;
  out[idx] =
      f16b(cw[((size_t)l * 4 * D * D + ((size_t)z * D + o) * D + c) * 3 + t]);
}

// ---- W_mix[b] = sum_z alpha[b,z] * W[z,center]  (f32 mix -> fp16) --------
__global__ __launch_bounds__(256) void wmix_k(const float* __restrict__ cw,
                                              const float* __restrict__ alpha,
                                              short* __restrict__ wm) {
  __shared__ float sal[64];
  if (threadIdx.x < 64) sal[threadIdx.x] = alpha[threadIdx.x];
  __syncthreads();
  const int idx = blockIdx.x * 256 + threadIdx.x;  // 262144 (o,c)
  const int c = idx & 511, o = idx >> 9;
  float w[4];
#pragma unroll
  for (int z = 0; z < 4; ++z)
    w[z] = cw[(((size_t)z * D + o) * D + c) * 3 + 1];
#pragma unroll
  for (int b = 0; b < 16; ++b) {
    const float v = sal[b * 4 + 0] * w[0] + sal[b * 4 + 1] * w[1] +
                    sal[b * 4 + 2] * w[2] + sal[b * 4 + 3] * w[3];
    wm[((size_t)b * D + o) * D + c] = f16b(v);
  }
}

__global__ __launch_bounds__(256) void zero_k(float* __restrict__ p) {
  p[threadIdx.x] = 0.f;
  p[threadIdx.x + 256] = 0.f;
}

// ---- alpha from GEMM column partials; cb_mix[b] = sum a_z cb_z -----------
__global__ __launch_bounds__(64) void alpha_k(const float* __restrict__ part,
                                              const float* __restrict__ wmw,
                                              const float* __restrict__ wmb,
                                              const float* __restrict__ cb,
                                              float* __restrict__ alpha,
                                              float* __restrict__ cbmix) {
  const int b = blockIdx.x, t = threadIdx.x;
  float p0 = 0, p1 = 0, p2 = 0, p3 = 0;
  for (int d = t; d < D; d += 64) {
    float xm = 0;
#pragma unroll
    for (int c = 0; c < 6; ++c) xm += part[((size_t)(b * 6 + c)) * D + d];
    xm *= (1.f / S);
    p0 += xm * wmw[d * 4 + 0];
    p1 += xm * wmw[d * 4 + 1];
    p2 += xm * wmw[d * 4 + 2];
    p3 += xm * wmw[d * 4 + 3];
  }
  p0 = wave_sum(p0); p1 = wave_sum(p1);
  p2 = wave_sum(p2); p3 = wave_sum(p3);
  const float l0 = p0 + wmb[0], l1 = p1 + wmb[1];
  const float l2 = p2 + wmb[2], l3 = p3 + wmb[3];
  const float mx = fmaxf(fmaxf(l0, l1), fmaxf(l2, l3));
  const float e0 = expf(l0 - mx), e1 = expf(l1 - mx);
  const float e2 = expf(l2 - mx), e3 = expf(l3 - mx);
  const float inv = 1.f / (e0 + e1 + e2 + e3);
  const float a0 = e0 * inv, a1 = e1 * inv, a2 = e2 * inv, a3 = e3 * inv;
  if (t == 0) {
    alpha[b * 4 + 0] = a0;
    alpha[b * 4 + 1] = a1;
    alpha[b * 4 + 2] = a2;
    alpha[b * 4 + 3] = a3;
  }
  for (int c = t; c < D; c += 64)
    cbmix[(size_t)b * D + c] =
        a0 * cb[c] + a1 * cb[D + c] + a2 * cb[2 * D + c] + a3 * cb[3 * D + c];
}

// ---- embedding gather-mean, hi-pack out ----------------------------------
__global__ __launch_bounds__(256) void embed_k(const int* __restrict__ xe,
                                               const float* __restrict__ emb,
                                               short* __restrict__ out) {
  const int r = blockIdx.x;
  int idx[8];
#pragma unroll
  for (int j = 0; j < 8; ++j) idx[j] = xe[r * 8 + j];
  short* o = out + (size_t)r * 512;
  for (int d = threadIdx.x; d < D; d += 256) {
    float s = 0.f;
#pragma unroll
    for (int j = 0; j < 8; ++j) s += emb[(size_t)idx[j] * D + d];
    o[d] = f16b(s * 0.125f);
  }
}

// ---- L2-normalize rows of (BS,64), hi-pack out ---------------------------
__global__ __launch_bounds__(256) void norml2_k(const float* __restrict__ x,
                                                short* __restrict__ out) {
  const int r = blockIdx.x * 4 + (threadIdx.x >> 6);
  const int lane = threadIdx.x & 63;
  const float v = x[(size_t)r * 64 + lane];
  const float s = wave_sum(v * v);
  const float nrm = fmaxf(sqrtf(s), 1e-12f);
  out[(size_t)r * 64 + lane] = f16b(v / nrm);
}

// ---- classifier head (reads GEMM column partials) ------------------------
__global__ __launch_bounds__(256) void head_k(
    const float* __restrict__ part, const float* __restrict__ pw1,
    const float* __restrict__ pb1, const float* __restrict__ pw2,
    const float* __restrict__ pb2, float* __restrict__ out) {
  __shared__ float hg[D];
  __shared__ float red[256];
  const int b = blockIdx.x, t = threadIdx.x;
  for (int d = t; d < D; d += 256) {
    float s = 0.f;
#pragma unroll
    for (int c = 0; c < 6; ++c) s += part[((size_t)(b * 6 + c)) * D + d];
    hg[d] = s * (1.f / S);
  }
  __syncthreads();
  float s = pb1[t];
  for (int d = 0; d < D; ++d) s = fmaf(hg[d], pw1[(size_t)d * 256 + t], s);
  s = fmaxf(s, 0.f);
  red[t] = s * pw2[t];
  __syncthreads();
  for (int o = 128; o > 0; o >>= 1) {
    if (t < o) red[t] += red[t + o];
    __syncthreads();
  }
  if (t == 0) out[b] = red[0] + pb2[0];
}

}  // namespace

extern "C" void kernel_launch(void* const* d_in, const int* in_sizes, int n_in,
                              void* d_out, int out_size, void* d_ws,
                              size_t ws_size, hipStream_t stream) {
  const float* x_cog = (const float*)d_in[0];
  const float* cw1 = (const float*)d_in[1];
  const float* cb1 = (const float*)d_in[2];
  const float* cw2 = (const float*)d_in[3];
  const float* cb2 = (const float*)d_in[4];
  const float* env_emb = (const float*)d_in[5];
  const float* ew1 = (const float*)d_in[6];
  const float* eb1 = (const float*)d_in[7];
  const float* ew2 = (const float*)d_in[8];
  const float* eb2 = (const float*)d_in[9];
  const float* fw1 = (const float*)d_in[10];
  const float* fb1 = (const float*)d_in[11];
  const float* fw2 = (const float*)d_in[12];
  const float* fb2 = (const float*)d_in[13];
  const float* pos_enc = (const float*)d_in[14];
  const float* conv_w = (const float*)d_in[15];
  const float* conv_b = (const float*)d_in[16];
  const float* wm_w = (const float*)d_in[17];
  const float* wm_b = (const float*)d_in[18];
  // d_in[19..21] = ssm_w/ssm_b/A_log: no-ops (y scalar-per-row cancels in LN2)
  const float* ffw1 = (const float*)d_in[22];
  const float* ffb1 = (const float*)d_in[23];
  const float* ffw2 = (const float*)d_in[24];
  const float* ffb2 = (const float*)d_in[25];
  const float* g1 = (const float*)d_in[26];
  const float* be1 = (const float*)d_in[27];
  const float* g2 = (const float*)d_in[28];
  const float* be2 = (const float*)d_in[29];
  const float* pw1 = (const float*)d_in[30];
  const float* pb1 = (const float*)d_in[31];
  const float* pw2 = (const float*)d_in[32];
  const float* pb2 = (const float*)d_in[33];
  const int* x_env = (const int*)d_in[34];
  float* out = (float*)d_out;

  // ---- arena (~173 MB) ----------------------------------------------------
  float* ws = (float*)d_ws;
  float* PART2 = ws;                       // 96x512 f32
  float* ALPHAB = PART2 + 65536;           // 64
  float* ZPADF = ALPHAB + 64;              // 512 zero page
  float* CBMIX = ZPADF + 512;              // 16x512 f32
  short* R = (short*)(CBMIX + 8192);
  short* WFFALL = R;                       // 6x2x1,048,576 [0, 12,582,912)
  short* WC8ALL = R + 12582912;            // 6x8x512x512   [12,582,912, 25,165,824)
  short* WMIX = R + 25165824;              // 16x512x512    [25,165,824, 29,360,128)
  short* convPh = R + 29360128;            // 2x12288x512   [29,360,128, 41,943,040)
  short* HPACK = R + 41943040;             // 12288x512     [41,943,040, 48,234,496)
  short* APFF = R + 48234496;              // 12288x2048    [48,234,496, 73,400,320)
  short* CONC = APFF;                      // frontend alias (CONC dead before
                                           // APFF first written in layer 0)
  short* PK1 = R + 73400320;               // 12288x512
  short* PK2 = R + 79691776;               // 12288x512
  short* WPBF = R + 85983232;              // frontend W pack (<=524,288)

  const dim3 blk(256);
  const dim3 gS(8, 96, 1);    // N=512, BN=64 -> 768 blocks (3/CU)
  const dim3 gF(16, 96, 1);   // N=2048, BN=128 -> 1536 blocks

  zero_k<<<1, blk, 0, stream>>>(ZPADF);
  pack_ff_all_k<<<3072, blk, 0, stream>>>(ffw1, ffw2, WFFALL);
  pack_conv8_all_k<<<49152, blk, 0, stream>>>(conv_w, WC8ALL);

  // ---- frontend -----------------------------------------------------------
  norml2_k<<<BS / 4, blk, 0, stream>>>(x_cog, PK1);
  pack_wt_k<<<dim3(8, 1), blk, 0, stream>>>(cw1, WPBF, 64, 512);
  gemm_h64<true, 0, true, false><<<gS, blk, 0, stream>>>(
      PK1, 64, WPBF, 64, 64, cb1, nullptr, nullptr, 0, 0, PK2, 512, nullptr);
  pack_wt_k<<<dim3(8, 8), blk, 0, stream>>>(cw2, WPBF, 512, 512);
  gemm_h64<false, 0, true, false><<<gS, blk, 0, stream>>>(
      PK2, 512, WPBF, 512, 512, cb2, nullptr, nullptr, 0, 0, CONC, 2048,
      nullptr);
  embed_k<<<BS, blk, 0, stream>>>(x_env, env_emb, PK1);
  pack_wt_k<<<dim3(8, 8), blk, 0, stream>>>(ew1, WPBF, 512, 512);
  gemm_h64<true, 0, true, false><<<gS, blk, 0, stream>>>(
      PK1, 512, WPBF, 512, 512, eb1, nullptr, nullptr, 0, 0, PK2, 512,
      nullptr);
  pack_wt_k<<<dim3(8, 8), blk, 0, stream>>>(ew2, WPBF, 512, 512);
  gemm_h64<false, 0, true, false><<<gS, blk, 0, stream>>>(
      PK2, 512, WPBF, 512, 512, eb2, nullptr, nullptr, 0, 0, CONC + 512, 2048,
      nullptr);
  pack_wt_k<<<dim3(8, 16), blk, 0, stream>>>(fw1, WPBF, 1024, 512);
  gemm_h64<true, 0, true, false><<<gS, blk, 0, stream>>>(
      CONC, 2048, WPBF, 1024, 1024, fb1, nullptr, nullptr, 0, 0, PK1, 512,
      nullptr);
  pack_wt_k<<<dim3(8, 8), blk, 0, stream>>>(fw2, WPBF, 512, 512);
  // h = (PK1@fw2 + fb2) + pos_enc -> HPACK hi + PART2 colsums
  gemm_h64<false, 1, true, true><<<gS, blk, 0, stream>>>(
      PK1, 512, WPBF, 512, 512, fb2, pos_enc, nullptr, 512, S, HPACK, 512,
      PART2);

  // ---- layers (all-f16 state, 6 dispatches each) -------------------------
  for (int l = 0; l < L; ++l) {
    const float* cwl = conv_w + (size_t)l * 4 * D * D * 3;
    alpha_k<<<B, dim3(64), 0, stream>>>(PART2, wm_w + (size_t)l * D * 4,
                                        wm_b + l * 4,
                                        conv_b + (size_t)l * 4 * D, ALPHAB,
                                        CBMIX);
    wmix_k<<<1024, blk, 0, stream>>>(cwl, ALPHAB, WMIX);
    conv_zp_k<<<768, blk, 0, stream>>>(HPACK, WC8ALL + (size_t)l * 2097152,
                                       WMIX, ALPHAB, (const short*)ZPADF,
                                       convPh);
    // h2 = LN2(LN1(P0+P1+h+cb_mix)) -> HPACK (in-place h -> h2)
    ln3_k<<<BS / 4, blk, 0, stream>>>(convPh, convPh + (size_t)BS * D, HPACK,
                                      CBMIX, g1 + l * D, be1 + l * D,
                                      g2 + l * D, be2 + l * D, HPACK);
    gemm_h<true, true><<<gF, blk, 0, stream>>>(
        HPACK, 512, WFFALL + (size_t)l * 2097152, 512, 512,
        ffb1 + (size_t)l * FF, APFF, 2048);
    // new h = APFF@ffw2 + ffb2 + h2(f16) -> HPACK (in-place) + PART2 colsums
    gemm_h64<false, 2, true, true><<<gS, blk, 0, stream>>>(
        APFF, 2048, WFFALL + (size_t)l * 2097152 + 1048576, 2048, 2048,
        ffb2 + (size_t)l * D, nullptr, HPACK, 512, 0, HPACK, 512, PART2);
  }

  // ---- head ---------------------------------------------------------------
  head_k<<<B, blk, 0, stream>>>(PART2, pw1, pb1, pw2, pb2, out);
}